// Round 6
// baseline (476.627 us; speedup 1.0000x reference)
//
#include <hip/hip_runtime.h>
#include <hip/hip_bf16.h>
#include <cstdint>
#include <cstddef>

#define N_NODES 50000
#define FDIM 512
#define NBKT 391        // ceil(50000/128) buckets of 128 dst nodes
#define CHUNK 8192      // edges per binning block
#define BCAP 4096       // max edges per bucket (mean 2046; huge headroom)

typedef __bf16 bf16_t;
typedef bf16_t bf16x8 __attribute__((ext_vector_type(8)));
typedef float f32x4 __attribute__((ext_vector_type(4)));

__device__ __forceinline__ unsigned short f2bf(float f) {
  union { float f; uint32_t u; } c; c.f = f;
  uint32_t u = c.u;
  uint32_t r = (u + 0x7fffu + ((u >> 16) & 1u)) >> 16;  // RNE
  return (unsigned short)r;
}
__device__ __forceinline__ float bf2f(unsigned short u) {
  union { uint32_t i; float f; } c; c.i = (uint32_t)u << 16; return c.f;
}
__device__ __forceinline__ float4 ld_bf4(const unsigned short* p) {
  ushort4 u = *(const ushort4*)p;
  float4 r; r.x = bf2f(u.x); r.y = bf2f(u.y); r.z = bf2f(u.z); r.w = bf2f(u.w);
  return r;
}
__device__ __forceinline__ void async16(const void* g, void* l) {
  __builtin_amdgcn_global_load_lds((const __attribute__((address_space(1))) void*)g,
                                   (__attribute__((address_space(3))) void*)l, 16, 0, 0);
}

// ---------------- CSR build: LDS-binned bucket sort, no global atomics ----------------
__global__ __launch_bounds__(256) void binA(const int* __restrict__ d1, const int* __restrict__ d2,
                                            int* __restrict__ M1, int* __restrict__ M2,
                                            int E1, int E2, int nch1, int nch2) {
  const int g = blockIdx.y;
  const int* dst = g ? d2 : d1;
  int* M = g ? M2 : M1;
  const int E = g ? E2 : E1;
  const int nch = g ? nch2 : nch1;
  const int chunk = blockIdx.x;
  if (chunk >= nch) return;
  __shared__ int cnt[NBKT];
  for (int j = threadIdx.x; j < NBKT; j += 256) cnt[j] = 0;
  __syncthreads();
  const int base = chunk * CHUNK;
#pragma unroll 4
  for (int i = 0; i < CHUNK / 256; i++) {
    int e = base + i * 256 + threadIdx.x;
    if (e < E) atomicAdd(&cnt[dst[e] >> 7], 1);
  }
  __syncthreads();
  for (int j = threadIdx.x; j < NBKT; j += 256) M[chunk * NBKT + j] = cnt[j];
}

__global__ __launch_bounds__(512) void bin_offsets(int* __restrict__ M1, int* __restrict__ M2,
                                                   int* __restrict__ bases,
                                                   int nch1, int nch2, int E1, int E2) {
  const int g = blockIdx.x;
  int* M = g ? M2 : M1;
  const int nch = g ? nch2 : nch1;
  int* base = bases + g * (NBKT + 1);
  const int E = g ? E2 : E1;
  const int t = threadIdx.x;
  __shared__ int tot[512];
  int running = 0;
  if (t < NBKT) {
    for (int b = 0; b < nch; b++) {
      int v = M[b * NBKT + t];
      M[b * NBKT + t] = running;
      running += v;
    }
  }
  tot[t] = (t < NBKT) ? running : 0;
  __syncthreads();
  for (int off = 1; off < 512; off <<= 1) {
    int u = (t >= off) ? tot[t - off] : 0;
    __syncthreads();
    tot[t] += u;
    __syncthreads();
  }
  int ex = (t == 0) ? 0 : tot[t - 1];
  if (t < NBKT) {
    base[t] = ex;
    for (int b = 0; b < nch; b++) M[b * NBKT + t] += ex;
  }
  if (t == NBKT) base[NBKT] = E;
}

__global__ __launch_bounds__(256) void binB(const int* __restrict__ s1, const int* __restrict__ d1,
                                            const int* __restrict__ M1, unsigned* __restrict__ eb1,
                                            int E1, int nch1,
                                            const int* __restrict__ s2, const int* __restrict__ d2,
                                            const int* __restrict__ M2, unsigned* __restrict__ eb2,
                                            int E2, int nch2) {
  const int g = blockIdx.y;
  const int* src = g ? s2 : s1;
  const int* dst = g ? d2 : d1;
  const int* M = g ? M2 : M1;
  unsigned* eb = g ? eb2 : eb1;
  const int E = g ? E2 : E1;
  const int nch = g ? nch2 : nch1;
  const int chunk = blockIdx.x;
  if (chunk >= nch) return;
  __shared__ int gbase[NBKT];
  __shared__ int cur[NBKT];
  for (int j = threadIdx.x; j < NBKT; j += 256) {
    gbase[j] = M[chunk * NBKT + j];
    cur[j] = 0;
  }
  __syncthreads();
  const int base = chunk * CHUNK;
#pragma unroll 4
  for (int i = 0; i < CHUNK / 256; i++) {
    int e = base + i * 256 + threadIdx.x;
    if (e < E) {
      int d = dst[e];
      int b = d >> 7;
      int pos = gbase[b] + atomicAdd(&cur[b], 1);
      eb[pos] = ((unsigned)d << 16) | (unsigned)src[e];
    }
  }
}

__global__ __launch_bounds__(256) void binC(const unsigned* __restrict__ eb1,
                                            const unsigned* __restrict__ eb2,
                                            const int* __restrict__ bases,
                                            int* __restrict__ rp1, float* __restrict__ dv1,
                                            int* __restrict__ cs1,
                                            int* __restrict__ rp2, float* __restrict__ dv2,
                                            int* __restrict__ cs2, int n) {
  const int g = blockIdx.y;
  const unsigned* eb = g ? eb2 : eb1;
  const int* base = bases + g * (NBKT + 1);
  int* rp = g ? rp2 : rp1;
  float* dv = g ? dv2 : dv1;
  int* cs = g ? cs2 : cs1;
  const int bkt = blockIdx.x;
  const int e0 = base[bkt], e1 = base[bkt + 1];
  const int cnt = e1 - e0;
  const int node0 = bkt << 7;
  const int t = threadIdx.x;
  __shared__ unsigned stage[BCAP];
  __shared__ int sorted[BCAP];
  __shared__ int dcnt[128], dcur[128], dscan[128];
  if (t < 128) dcnt[t] = 0;
  __syncthreads();
  for (int i = t; i < cnt; i += 256) {
    unsigned pe = eb[e0 + i];
    stage[i] = pe;
    atomicAdd(&dcnt[(pe >> 16) & 127], 1);
  }
  __syncthreads();
  if (t < 128) dscan[t] = dcnt[t];
  __syncthreads();
  for (int off = 1; off < 128; off <<= 1) {
    int u = (t < 128 && t >= off) ? dscan[t - off] : 0;
    __syncthreads();
    if (t < 128) dscan[t] += u;
    __syncthreads();
  }
  if (t < 128) {
    int ex = dscan[t] - dcnt[t];
    dcur[t] = ex;
    int node = node0 + t;
    if (node < n) {
      rp[node] = e0 + ex;
      dv[node] = rsqrtf((float)dcnt[t] + 1.0f);  // deg includes self-loop
    }
  }
  __syncthreads();
  for (int i = t; i < cnt; i += 256) {
    unsigned pe = stage[i];
    int d = (pe >> 16) & 127;
    int pos = atomicAdd(&dcur[d], 1);
    sorted[pos] = (int)(pe & 0xFFFFu);
  }
  __syncthreads();
  for (int i = t; i < cnt; i += 256) cs[e0 + i] = sorted[i];
  if (bkt == NBKT - 1 && t == 0) rp[n] = base[NBKT];
}

// ---------------- weight converts ----------------
// WcatT[384][512] (cols of [W10|W20], zero-pad), W21T[256][64], WfcT[16][256]
__global__ void cvt_w(const float* __restrict__ W10, const float* __restrict__ W20,
                      const float* __restrict__ W21, const float* __restrict__ Wfc,
                      unsigned short* __restrict__ WcatT, unsigned short* __restrict__ W21T,
                      unsigned short* __restrict__ WfcT) {
  int j = blockIdx.x * 256 + threadIdx.x;
  const int T1 = 384 * 512, T2 = 256 * 64, T3 = 16 * 256;
  if (j < T1) {
    int n = j >> 9, k = j & 511;
    float v = (n < 256) ? W10[k * 256 + n] : ((n < 320) ? W20[k * 64 + (n - 256)] : 0.f);
    WcatT[j] = f2bf(v);
  } else if (j < T1 + T2) {
    int j2 = j - T1;
    int n = j2 >> 6, k = j2 & 63;
    W21T[j2] = f2bf(W21[k * 256 + n]);
  } else if (j < T1 + T2 + T3) {
    int j3 = j - T1 - T2;
    int c = j3 >> 8, k = j3 & 255;
    WfcT[j3] = f2bf(Wfc[k * 16 + c]);
  }
}

// ---------------- gemm_x: [Xh1b|Xh2b] = bf16( dinv ⊙ (X @ [W10|W20]) ) ----------------
// A fp32 (converted during staging — no cvt_x pass). tile 128(M) x 192(N), BK=64,
// 256 threads / 4 waves in 2x2, wave 64(M) x 96(N), acc[4][6]. grid (391, 2).
__global__ __launch_bounds__(256) void gemm_x(const float* __restrict__ X,
                                              const unsigned short* __restrict__ WcatT,
                                              const float* __restrict__ dinv1,
                                              const float* __restrict__ dinv2,
                                              unsigned short* __restrict__ Xh1b,
                                              unsigned short* __restrict__ Xh2b, int M) {
  __shared__ unsigned short As[128 * 64];
  __shared__ unsigned short Bs[192 * 64];
  const int tid = threadIdx.x;
  const int w = tid >> 6, lane = tid & 63;
  const int row0 = blockIdx.x * 128;
  const int n0 = blockIdx.y * 192;
  const int wm = w >> 1, wn = w & 1;
  const int lr = lane >> 3, lc8 = (lane & 7) * 8;
  const int mlane = lane & 15, q = lane >> 4;

  f32x4 acc[4][6];
#pragma unroll
  for (int mi = 0; mi < 4; mi++)
#pragma unroll
    for (int ni = 0; ni < 6; ni++) {
      f32x4 z = {0.f, 0.f, 0.f, 0.f};
      acc[mi][ni] = z;
    }

  for (int k0 = 0; k0 < 512; k0 += 64) {
    __syncthreads();
    // A: load fp32, convert to bf16, ds_write (128 rows x 64 k = 2048 float4 / 256 thr)
#pragma unroll
    for (int j = 0; j < 4; j++) {
      int idx = j * 512 + tid;          // wait: 4*512 covers 2048 with 256 threads? no.
      // 2048 slots / 256 threads = 8 rounds of 256
      (void)idx;
    }
#pragma unroll
    for (int j = 0; j < 8; j++) {
      int idx = j * 256 + tid;          // 0..2047
      int r = idx >> 4, f4 = idx & 15;
      int gr = row0 + r; if (gr > M - 1) gr = M - 1;
      float4 v = *(const float4*)(X + (size_t)gr * 512 + k0 + f4 * 4);
      ushort4 o; o.x = f2bf(v.x); o.y = f2bf(v.y); o.z = f2bf(v.z); o.w = f2bf(v.w);
      *(ushort4*)&As[r * 64 + f4 * 4] = o;
    }
    // B: async16, 192 rows (6 rounds x 4 waves x 8 rows)
#pragma unroll
    for (int j = 0; j < 6; j++) {
      int r = j * 32 + w * 8 + lr;
      async16(WcatT + (size_t)(n0 + r) * 512 + k0 + lc8, &Bs[(j * 32 + w * 8) * 64]);
    }
    __syncthreads();
#pragma unroll
    for (int kk = 0; kk < 2; kk++) {
      bf16x8 af[4], bfr[6];
#pragma unroll
      for (int mi = 0; mi < 4; mi++)
        af[mi] = *(const bf16x8*)&As[(wm * 64 + mi * 16 + mlane) * 64 + kk * 32 + q * 8];
#pragma unroll
      for (int ni = 0; ni < 6; ni++)
        bfr[ni] = *(const bf16x8*)&Bs[(wn * 96 + ni * 16 + mlane) * 64 + kk * 32 + q * 8];
#pragma unroll
      for (int mi = 0; mi < 4; mi++)
#pragma unroll
        for (int ni = 0; ni < 6; ni++)
          acc[mi][ni] = __builtin_amdgcn_mfma_f32_16x16x32_bf16(af[mi], bfr[ni], acc[mi][ni], 0, 0, 0);
    }
  }

#pragma unroll
  for (int mi = 0; mi < 4; mi++)
#pragma unroll
    for (int rg = 0; rg < 4; rg++) {
      int r = row0 + wm * 64 + mi * 16 + q * 4 + rg;
      if (r >= M) continue;
      float dv1 = dinv1[r], dv2 = dinv2[r];
#pragma unroll
      for (int ni = 0; ni < 6; ni++) {
        int c = n0 + wn * 96 + ni * 16 + mlane;
        float v = acc[mi][ni][rg];
        if (c < 256) Xh1b[(size_t)r * 256 + c] = f2bf(v * dv1);
        else if (c < 320) Xh2b[(size_t)r * 64 + (c - 256)] = f2bf(v * dv2);
      }
    }
}

// ---------------- propagation (pre-scaled rows: out = di*(self' + Σ rows') ) ------------
__global__ __launch_bounds__(256) void prop256(const unsigned short* __restrict__ H,
                                               const int* __restrict__ rp,
                                               const int* __restrict__ cs,
                                               const float* __restrict__ dinv,
                                               const float* __restrict__ bias,
                                               unsigned short* __restrict__ out, int n) {
  const int i = blockIdx.x * 4 + (threadIdx.x >> 6);
  const int l = threadIdx.x & 63;
  if (i >= n) return;
  const float di = dinv[i];
  float4 acc = ld_bf4(H + (size_t)i * 256 + l * 4);  // self already scaled
  const int e1 = rp[i + 1];
#pragma unroll 8
  for (int e = rp[i]; e < e1; e++) {
    float4 rrow = ld_bf4(H + (size_t)cs[e] * 256 + l * 4);
    acc.x += rrow.x; acc.y += rrow.y; acc.z += rrow.z; acc.w += rrow.w;
  }
  float4 b = *(const float4*)(bias + l * 4);
  ushort4 o;
  o.x = f2bf(fmaxf(di * acc.x + b.x, 0.f));
  o.y = f2bf(fmaxf(di * acc.y + b.y, 0.f));
  o.z = f2bf(fmaxf(di * acc.z + b.z, 0.f));
  o.w = f2bf(fmaxf(di * acc.w + b.w, 0.f));
  *(ushort4*)(out + (size_t)i * 256 + l * 4) = o;
}

// 64-dim. MODE 1: out = (di*acc + b)*di  (h2, stored pre-scaled for next prop)
// MODE 0: out = di*acc                   (q2, feeds GEMM)
template <int MODE>
__global__ __launch_bounds__(256) void prop64(const unsigned short* __restrict__ H,
                                              const int* __restrict__ rp,
                                              const int* __restrict__ cs,
                                              const float* __restrict__ dinv,
                                              const float* __restrict__ bias,
                                              unsigned short* __restrict__ out, int n) {
  const int i = blockIdx.x * 16 + (threadIdx.x >> 4);
  const int l = threadIdx.x & 15;
  if (i >= n) return;
  const float di = dinv[i];
  float4 acc = ld_bf4(H + (size_t)i * 64 + l * 4);
  const int e1 = rp[i + 1];
#pragma unroll 8
  for (int e = rp[i]; e < e1; e++) {
    float4 rrow = ld_bf4(H + (size_t)cs[e] * 64 + l * 4);
    acc.x += rrow.x; acc.y += rrow.y; acc.z += rrow.z; acc.w += rrow.w;
  }
  float4 o;
  if (MODE) {
    float4 b = *(const float4*)(bias + l * 4);
    o.x = (di * acc.x + b.x) * di; o.y = (di * acc.y + b.y) * di;
    o.z = (di * acc.z + b.z) * di; o.w = (di * acc.w + b.w) * di;
  } else {
    o.x = di * acc.x; o.y = di * acc.y; o.z = di * acc.z; o.w = di * acc.w;
  }
  ushort4 ob;
  ob.x = f2bf(o.x); ob.y = f2bf(o.y); ob.z = f2bf(o.z); ob.w = f2bf(o.w);
  *(ushort4*)(out + (size_t)i * 64 + l * 4) = ob;
}

// ---------------- gemm2_final: out = (relu(q2@W21 + b21) + h1) @ Wfc + bfc ----------------
// Block: 64 rows. Phase 1: 64x256 = q2[64x64] @ W21T (single K-tile). 4 waves 2x2,
// wave 32(M)x128(N), acc[2][8]. Phase 2: h (LDS bf16) @ WfcT[16][256] -> out[64x16].
__global__ __launch_bounds__(256) void gemm2_final(const unsigned short* __restrict__ q2,
                                                   const unsigned short* __restrict__ W21T,
                                                   const unsigned short* __restrict__ WfcT,
                                                   const unsigned short* __restrict__ h1,
                                                   const float* __restrict__ b21,
                                                   const float* __restrict__ bfc,
                                                   float* __restrict__ out, int M) {
  __shared__ unsigned short As[64 * 64];    // q2 tile
  __shared__ unsigned short Bs[256 * 64];   // W21T
  __shared__ unsigned short Hs[64 * 256];   // h tile (phase-2 A)
  __shared__ unsigned short Ws[16 * 256];   // WfcT (phase-2 B)
  const int tid = threadIdx.x;
  const int w = tid >> 6, lane = tid & 63;
  const int row0 = blockIdx.x * 64;
  const int wm = w >> 1, wn = w & 1;
  const int lr = lane >> 3, lc8 = (lane & 7) * 8;
  const int mlane = lane & 15, q = lane >> 4;

  // stage q2 (64x64), W21T (256x64), WfcT (4096 flat)
#pragma unroll
  for (int j = 0; j < 2; j++) {
    int r = j * 32 + w * 8 + lr;
    int gr = row0 + r; if (gr > M - 1) gr = M - 1;
    async16(q2 + (size_t)gr * 64 + lc8, &As[(j * 32 + w * 8) * 64]);
  }
#pragma unroll
  for (int j = 0; j < 8; j++) {
    int r = j * 32 + w * 8 + lr;
    async16(W21T + (size_t)r * 64 + lc8, &Bs[(j * 32 + w * 8) * 64]);
  }
#pragma unroll
  for (int j = 0; j < 2; j++) {
    int base = (j * 4 + w) * 512;
    async16(WfcT + base + lane * 8, &Ws[base]);
  }
  __syncthreads();

  f32x4 acc[2][8];
#pragma unroll
  for (int mi = 0; mi < 2; mi++)
#pragma unroll
    for (int ni = 0; ni < 8; ni++) {
      f32x4 z = {0.f, 0.f, 0.f, 0.f};
      acc[mi][ni] = z;
    }
#pragma unroll
  for (int kk = 0; kk < 2; kk++) {
    bf16x8 af[2], bfr[8];
#pragma unroll
    for (int mi = 0; mi < 2; mi++)
      af[mi] = *(const bf16x8*)&As[(wm * 32 + mi * 16 + mlane) * 64 + kk * 32 + q * 8];
#pragma unroll
    for (int ni = 0; ni < 8; ni++)
      bfr[ni] = *(const bf16x8*)&Bs[(wn * 128 + ni * 16 + mlane) * 64 + kk * 32 + q * 8];
#pragma unroll
    for (int mi = 0; mi < 2; mi++)
#pragma unroll
      for (int ni = 0; ni < 8; ni++)
        acc[mi][ni] = __builtin_amdgcn_mfma_f32_16x16x32_bf16(af[mi], bfr[ni], acc[mi][ni], 0, 0, 0);
  }

  // h = relu(acc + b21) + h1  -> Hs (bf16)
#pragma unroll
  for (int mi = 0; mi < 2; mi++)
#pragma unroll
    for (int ni = 0; ni < 8; ni++) {
      int c = wn * 128 + ni * 16 + mlane;
      float bb = b21[c];
#pragma unroll
      for (int rg = 0; rg < 4; rg++) {
        int rl = wm * 32 + mi * 16 + q * 4 + rg;
        int gr = row0 + rl;
        float v = 0.f;
        if (gr < M)
          v = fmaxf(acc[mi][ni][rg] + bb, 0.f) + bf2f(h1[(size_t)gr * 256 + c]);
        Hs[rl * 256 + c] = f2bf(v);
      }
    }
  __syncthreads();

  // phase 2: wave w -> rows w*16..w*16+15; out[64x16]
  f32x4 a2 = {0.f, 0.f, 0.f, 0.f};
#pragma unroll
  for (int k0 = 0; k0 < 8; k0++) {
    bf16x8 af = *(const bf16x8*)&Hs[(w * 16 + mlane) * 256 + k0 * 32 + q * 8];
    bf16x8 bfr = *(const bf16x8*)&Ws[mlane * 256 + k0 * 32 + q * 8];
    a2 = __builtin_amdgcn_mfma_f32_16x16x32_bf16(af, bfr, a2, 0, 0, 0);
  }
  const float bo = bfc[mlane];
#pragma unroll
  for (int rg = 0; rg < 4; rg++) {
    int gr = row0 + w * 16 + q * 4 + rg;
    if (gr < M) out[(size_t)gr * 16 + mlane] = a2[rg] + bo;
  }
}

// ---------------- launch ----------------
extern "C" void kernel_launch(void* const* d_in, const int* in_sizes, int n_in,
                              void* d_out, int out_size, void* d_ws, size_t ws_size,
                              hipStream_t stream) {
  const float* X   = (const float*)d_in[0];
  const int*   ei1 = (const int*)d_in[1];
  const int*   ei2 = (const int*)d_in[2];
  const float* W10 = (const float*)d_in[3];
  const float* b10 = (const float*)d_in[4];
  const float* W20 = (const float*)d_in[5];
  const float* b20 = (const float*)d_in[6];
  const float* W21 = (const float*)d_in[7];
  const float* b21 = (const float*)d_in[8];
  const float* Wfc = (const float*)d_in[9];
  const float* bfc = (const float*)d_in[10];
  float* out = (float*)d_out;

  const int N = N_NODES;
  const int E1 = in_sizes[1] / 2, E2 = in_sizes[2] / 2;
  const int* src1 = ei1; const int* dst1 = ei1 + E1;
  const int* src2 = ei2; const int* dst2 = ei2 + E2;
  const int nch1 = (E1 + CHUNK - 1) / CHUNK, nch2 = (E2 + CHUNK - 1) / CHUNK;
  const int nchmax = (nch1 > nch2) ? nch1 : nch2;

  char* p = (char*)d_ws;
  auto alloc = [&](size_t b) { char* r = p; p += (b + 255) & ~(size_t)255; return (void*)r; };
  int* M1 = (int*)alloc((size_t)nch1 * NBKT * 4);
  int* M2 = (int*)alloc((size_t)nch2 * NBKT * 4);
  int* bases = (int*)alloc((size_t)2 * (NBKT + 1) * 4);
  unsigned* eb1 = (unsigned*)alloc((size_t)E1 * 4);
  unsigned* eb2 = (unsigned*)alloc((size_t)E2 * 4);
  int* rp1 = (int*)alloc((size_t)(N + 1) * 4);
  int* rp2 = (int*)alloc((size_t)(N + 1) * 4);
  float* dinv1 = (float*)alloc((size_t)N * 4);
  float* dinv2 = (float*)alloc((size_t)N * 4);
  int* csr1s = (int*)alloc((size_t)E1 * 4);
  int* csr2s = (int*)alloc((size_t)E2 * 4);
  unsigned short* WcatT = (unsigned short*)alloc(384 * 512 * 2);
  unsigned short* W21T  = (unsigned short*)alloc(256 * 64 * 2);
  unsigned short* WfcT  = (unsigned short*)alloc(16 * 256 * 2);
  unsigned short* Xh1b = (unsigned short*)alloc((size_t)N * 256 * 2);  // dinv1-scaled
  unsigned short* Xh2b = (unsigned short*)alloc((size_t)N * 64 * 2);   // dinv2-scaled
  unsigned short* h2b  = (unsigned short*)alloc((size_t)N * 64 * 2);   // dinv2-scaled h2
  unsigned short* q2b  = (unsigned short*)alloc((size_t)N * 64 * 2);
  unsigned short* h1b  = (unsigned short*)alloc((size_t)N * 256 * 2);

  // CSR build (no global atomics)
  binA<<<dim3(nchmax, 2), 256, 0, stream>>>(dst1, dst2, M1, M2, E1, E2, nch1, nch2);
  bin_offsets<<<dim3(2), 512, 0, stream>>>(M1, M2, bases, nch1, nch2, E1, E2);
  binB<<<dim3(nchmax, 2), 256, 0, stream>>>(src1, dst1, M1, eb1, E1, nch1,
                                            src2, dst2, M2, eb2, E2, nch2);
  binC<<<dim3(NBKT, 2), 256, 0, stream>>>(eb1, eb2, bases, rp1, dinv1, csr1s,
                                          rp2, dinv2, csr2s, N);
  cvt_w<<<dim3((384 * 512 + 256 * 64 + 16 * 256 + 255) / 256), 256, 0, stream>>>(
      W10, W20, W21, Wfc, WcatT, W21T, WfcT);
  // Xh1b = bf16(dinv1 ⊙ x@W10), Xh2b = bf16(dinv2 ⊙ x@W20); converts X on the fly
  gemm_x<<<dim3((N + 127) / 128, 2), 256, 0, stream>>>(X, WcatT, dinv1, dinv2, Xh1b, Xh2b, N);
  // h1 = relu(prop1 + b10) -> bf16
  prop256<<<dim3((N + 3) / 4), 256, 0, stream>>>(Xh1b, rp1, csr1s, dinv1, b10, h1b, N);
  // h2' = (prop2 + b20)*dinv2 -> bf16
  prop64<1><<<dim3((N + 15) / 16), 256, 0, stream>>>(Xh2b, rp2, csr2s, dinv2, b20, h2b, N);
  // q2 = prop2(h2) -> bf16
  prop64<0><<<dim3((N + 15) / 16), 256, 0, stream>>>(h2b, rp2, csr2s, dinv2, nullptr, q2b, N);
  // out = (relu(q2@W21 + b21) + h1) @ Wfc + bfc   (fused, h3 never materialized)
  gemm2_final<<<dim3((N + 63) / 64), 256, 0, stream>>>(q2b, W21T, WfcT, h1b, b21, bfc, out, N);
}